// Round 1
// baseline (1045.492 us; speedup 1.0000x reference)
//
#include <hip/hip_runtime.h>
#include <hip/hip_bf16.h>
#include <math.h>

#define NODES 100000
#define NEDGE 1600000
#define DIN 64
#define NH 4
#define NF 16

// ---------------- K1: node transform ----------------
// z = feat @ W^T (N,64); el/er per (n,h); inv_s per (n,f)
__global__ __launch_bounds__(256) void node_transform(
    const float* __restrict__ feat, const float* __restrict__ W,
    const float* __restrict__ attn_l, const float* __restrict__ attn_r,
    float* __restrict__ z, float* __restrict__ el, float* __restrict__ er,
    float* __restrict__ inv_s, int n)
{
    __shared__ float Wt[64 * 65];   // transposed + padded: Wt[d*65+o] = W[o*64+d]
    for (int i = threadIdx.x; i < 4096; i += 256) {
        int r = i >> 6, c = i & 63;
        Wt[c * 65 + r] = W[i];
    }
    __syncthreads();

    int lane = threadIdx.x & 63;
    int h = lane >> 4, f = lane & 15;
    float al = attn_l[lane];
    float ar = attn_r[lane];

    int nidx = blockIdx.x * 4 + (threadIdx.x >> 6);
    if (nidx >= n) return;

    float fv = feat[nidx * 64 + lane];
    float zv = 0.f;
#pragma unroll
    for (int d = 0; d < 64; d++) {
        zv += __shfl(fv, d) * Wt[d * 65 + lane];
    }

    // el/er: reduce over f within each 16-lane head group
    float elv = zv * al, erv = zv * ar;
#pragma unroll
    for (int o = 1; o < 16; o <<= 1) {
        elv += __shfl_xor(elv, o);
        erv += __shfl_xor(erv, o);
    }
    // s[f] = sum over heads of z^2 (lanes with same f differ in bits 4,5)
    float sq = zv * zv;
    sq += __shfl_xor(sq, 16);
    sq += __shfl_xor(sq, 32);
    float isv = 1.0f / fmaxf(sq, 1e-3f);

    z[nidx * 64 + lane] = zv;
    if (f == 0) {
        el[nidx * 4 + h] = elv;
        er[nidx * 4 + h] = erv;
    }
    if (h == 0) inv_s[nidx * 16 + f] = isv;
}

// ---------------- CSR build ----------------
__global__ void count_k(const int* __restrict__ dst, int e_n, int* __restrict__ cnt)
{
    int e = blockIdx.x * 256 + threadIdx.x;
    if (e < e_n) atomicAdd(&cnt[dst[e]], 1);
}

// per-block (1024 elems) exclusive scan; block totals to blksum
__global__ __launch_bounds__(256) void scan1(const int* __restrict__ cnt, int n,
                                             int* __restrict__ excl, int* __restrict__ blksum)
{
    __shared__ int sums[256];
    int t = threadIdx.x;
    int base = blockIdx.x * 1024 + t * 4;
    int v[4];
    int tot = 0;
#pragma unroll
    for (int k = 0; k < 4; k++) {
        int idx = base + k;
        v[k] = (idx < n) ? cnt[idx] : 0;
        tot += v[k];
    }
    sums[t] = tot;
    __syncthreads();
    for (int off = 1; off < 256; off <<= 1) {
        int x = (t >= off) ? sums[t - off] : 0;
        __syncthreads();
        sums[t] += x;
        __syncthreads();
    }
    int run = sums[t] - tot;  // exclusive prefix within block
#pragma unroll
    for (int k = 0; k < 4; k++) {
        int idx = base + k;
        if (idx < n) excl[idx] = run;
        run += v[k];
    }
    if (t == 255) blksum[blockIdx.x] = sums[255];
}

__global__ __launch_bounds__(128) void scan2(int* __restrict__ blksum, int nb)
{
    __shared__ int s[128];
    int t = threadIdx.x;
    int v = (t < nb) ? blksum[t] : 0;
    s[t] = v;
    __syncthreads();
    for (int off = 1; off < 128; off <<= 1) {
        int x = (t >= off) ? s[t - off] : 0;
        __syncthreads();
        s[t] += x;
        __syncthreads();
    }
    if (t < nb) blksum[t] = s[t] - v;  // exclusive
}

__global__ void scan3(const int* __restrict__ blksum, int n, int e_n, int* __restrict__ row_ptr)
{
    int i = blockIdx.x * 256 + threadIdx.x;
    if (i < n) row_ptr[i] = row_ptr[i] + blksum[i >> 10];
    if (i == n) row_ptr[n] = e_n;
}

__global__ void scatter_k(const int* __restrict__ dst, int e_n,
                          const int* __restrict__ row_ptr, int* __restrict__ cur,
                          int* __restrict__ perm)
{
    int e = blockIdx.x * 256 + threadIdx.x;
    if (e < e_n) {
        int d = dst[e];
        int p = atomicAdd(&cur[d], 1);
        perm[row_ptr[d] + p] = e;
    }
}

// ---------------- K3: per-edge scores ----------------
__global__ void edge_score(const float* __restrict__ z, const float* __restrict__ el,
                           const float* __restrict__ er, const float* __restrict__ inv_s,
                           const int* __restrict__ src, const int* __restrict__ dst,
                           float* __restrict__ escore, int e_n)
{
    int e = blockIdx.x * 256 + threadIdx.x;
    if (e >= e_n) return;
    int u = src[e], v = dst[e];
    const float4* zu = (const float4*)(z + (size_t)u * 64);
    const float4* zv = (const float4*)(z + (size_t)v * 64);
    float edp[4] = {0.f, 0.f, 0.f, 0.f};
#pragma unroll
    for (int i = 0; i < 16; i++) {
        float4 a = zu[i], b = zv[i];
        edp[i >> 2] += a.x * b.x + a.y * b.y + a.z * b.z + a.w * b.w;
    }
    const float4* iu = (const float4*)(inv_s + (size_t)u * 16);
    const float4* iv = (const float4*)(inv_s + (size_t)v * 16);
    float ff = 0.f;
#pragma unroll
    for (int i = 0; i < 4; i++) {
        float4 a = iu[i], b = iv[i];
        ff += a.x * b.x + a.y * b.y + a.z * b.z + a.w * b.w;
    }
    float4 elu = *(const float4*)(el + (size_t)u * 4);
    float4 erv = *(const float4*)(er + (size_t)v * 4);
    float4 out;
    out.x = fmaxf(edp[0] * ff, 0.f) * (elu.x + erv.x);
    out.y = fmaxf(edp[1] * ff, 0.f) * (elu.y + erv.y);
    out.z = fmaxf(edp[2] * ff, 0.f) * (elu.z + erv.z);
    out.w = fmaxf(edp[3] * ff, 0.f) * (elu.w + erv.w);
    ((float4*)escore)[e] = out;
}

// ---------------- K4: softmax + aggregate (one wave per dst node) ----------------
__global__ __launch_bounds__(256) void node_aggregate(
    const float* __restrict__ z, const float* __restrict__ escore,
    const int* __restrict__ row_ptr, const int* __restrict__ perm,
    const int* __restrict__ src, float* __restrict__ out, int n)
{
    int lane = threadIdx.x & 63;
    int h = lane >> 4;
    int nidx = blockIdx.x * 4 + (threadIdx.x >> 6);
    if (nidx >= n) return;

    int s0 = row_ptr[nidx], s1 = row_ptr[nidx + 1];
    float m = -INFINITY;
    for (int i = s0; i < s1; i++) {
        int e = perm[i];
        m = fmaxf(m, escore[e * 4 + h]);
    }
    float denom = 0.f, acc = 0.f;
    for (int i = s0; i < s1; i++) {
        int e = perm[i];
        float p = __expf(escore[e * 4 + h] - m);
        denom += p;
        acc += p * z[(size_t)src[e] * 64 + lane];
    }
    out[nidx * 64 + lane] = (s1 > s0) ? (acc / denom) : 0.f;
}

extern "C" void kernel_launch(void* const* d_in, const int* in_sizes, int n_in,
                              void* d_out, int out_size, void* d_ws, size_t ws_size,
                              hipStream_t stream)
{
    const float* feat   = (const float*)d_in[0];
    const int*   src    = (const int*)d_in[1];
    const int*   dst    = (const int*)d_in[2];
    const float* W      = (const float*)d_in[3];
    const float* attn_l = (const float*)d_in[4];
    const float* attn_r = (const float*)d_in[5];
    float* out = (float*)d_out;

    const int n = in_sizes[0] / DIN;   // 100000
    const int e_n = in_sizes[1];       // 1600000

    // workspace layout
    float* z      = (float*)d_ws;              // n*64
    float* el     = z + (size_t)n * 64;        // n*4
    float* er     = el + (size_t)n * 4;        // n*4
    float* inv_s  = er + (size_t)n * 4;        // n*16
    float* escore = inv_s + (size_t)n * 16;    // e_n*4
    int* row_ptr  = (int*)(escore + (size_t)e_n * 4);  // n+1
    int* cnt      = row_ptr + (n + 1);         // n
    int* perm     = cnt + n;                   // e_n
    int* blksum   = perm + e_n;                // 128

    int nb = (n + 1023) / 1024;

    // K1: node transform
    hipLaunchKernelGGL(node_transform, dim3((n + 3) / 4), dim3(256), 0, stream,
                       feat, W, attn_l, attn_r, z, el, er, inv_s, n);

    // CSR build
    hipMemsetAsync(cnt, 0, (size_t)n * sizeof(int), stream);
    hipLaunchKernelGGL(count_k, dim3((e_n + 255) / 256), dim3(256), 0, stream, dst, e_n, cnt);
    hipLaunchKernelGGL(scan1, dim3(nb), dim3(256), 0, stream, cnt, n, row_ptr, blksum);
    hipLaunchKernelGGL(scan2, dim3(1), dim3(128), 0, stream, blksum, nb);
    hipLaunchKernelGGL(scan3, dim3((n + 1 + 255) / 256), dim3(256), 0, stream, blksum, n, e_n, row_ptr);
    hipMemsetAsync(cnt, 0, (size_t)n * sizeof(int), stream);
    hipLaunchKernelGGL(scatter_k, dim3((e_n + 255) / 256), dim3(256), 0, stream,
                       dst, e_n, row_ptr, cnt, perm);

    // K3: edge scores
    hipLaunchKernelGGL(edge_score, dim3((e_n + 255) / 256), dim3(256), 0, stream,
                       z, el, er, inv_s, src, dst, escore, e_n);

    // K4: softmax + aggregate
    hipLaunchKernelGGL(node_aggregate, dim3((n + 3) / 4), dim3(256), 0, stream,
                       z, escore, row_ptr, perm, src, out, n);
}

// Round 2
// 512.048 us; speedup vs baseline: 2.0418x; 2.0418x over previous
//
#include <hip/hip_runtime.h>
#include <hip/hip_bf16.h>
#include <math.h>

#define DIN 64
#define NH 4
#define NF 16
#define RECF 96   // floats per packed node record: z[64], inv_s[16], el[4], er[4], pad[8]

// ---------------- K1: node transform -> packed record ----------------
// rec[n] = { z[0..64), inv_s[64..80), el[80..84), er[84..88) }
__global__ __launch_bounds__(256) void node_transform(
    const float* __restrict__ feat, const float* __restrict__ W,
    const float* __restrict__ attn_l, const float* __restrict__ attn_r,
    float* __restrict__ rec, int n)
{
    __shared__ float Wt[64 * 65];   // transposed + padded: Wt[d*65+o] = W[o*64+d]
    for (int i = threadIdx.x; i < 4096; i += 256) {
        int r = i >> 6, c = i & 63;
        Wt[c * 65 + r] = W[i];
    }
    __syncthreads();

    int lane = threadIdx.x & 63;
    int h = lane >> 4, f = lane & 15;
    float al = attn_l[lane];
    float ar = attn_r[lane];

    int nidx = blockIdx.x * 4 + (threadIdx.x >> 6);
    if (nidx >= n) return;

    float fv = feat[nidx * 64 + lane];
    float zv = 0.f;
#pragma unroll
    for (int d = 0; d < 64; d++) {
        zv += __shfl(fv, d) * Wt[d * 65 + lane];
    }

    // el/er: reduce over f within each 16-lane head group
    float elv = zv * al, erv = zv * ar;
#pragma unroll
    for (int o = 1; o < 16; o <<= 1) {
        elv += __shfl_xor(elv, o);
        erv += __shfl_xor(erv, o);
    }
    // s[f] = sum over heads of z^2 (lanes with same f differ in bits 4,5)
    float sq = zv * zv;
    sq += __shfl_xor(sq, 16);
    sq += __shfl_xor(sq, 32);
    float isv = 1.0f / fmaxf(sq, 1e-3f);

    float* r = rec + (size_t)nidx * RECF;
    r[lane] = zv;
    if (h == 0) r[64 + f] = isv;
    if (f == 0) {
        r[80 + h] = elv;
        r[84 + h] = erv;
    }
}

// ---------------- CSR build ----------------
__global__ void count_k(const int* __restrict__ dst, int e_n, int* __restrict__ cnt)
{
    int e = blockIdx.x * 256 + threadIdx.x;
    if (e < e_n) atomicAdd(&cnt[dst[e]], 1);
}

__global__ __launch_bounds__(256) void scan1(const int* __restrict__ cnt, int n,
                                             int* __restrict__ excl, int* __restrict__ blksum)
{
    __shared__ int sums[256];
    int t = threadIdx.x;
    int base = blockIdx.x * 1024 + t * 4;
    int v[4];
    int tot = 0;
#pragma unroll
    for (int k = 0; k < 4; k++) {
        int idx = base + k;
        v[k] = (idx < n) ? cnt[idx] : 0;
        tot += v[k];
    }
    sums[t] = tot;
    __syncthreads();
    for (int off = 1; off < 256; off <<= 1) {
        int x = (t >= off) ? sums[t - off] : 0;
        __syncthreads();
        sums[t] += x;
        __syncthreads();
    }
    int run = sums[t] - tot;
#pragma unroll
    for (int k = 0; k < 4; k++) {
        int idx = base + k;
        if (idx < n) excl[idx] = run;
        run += v[k];
    }
    if (t == 255) blksum[blockIdx.x] = sums[255];
}

__global__ __launch_bounds__(128) void scan2(int* __restrict__ blksum, int nb)
{
    __shared__ int s[128];
    int t = threadIdx.x;
    int v = (t < nb) ? blksum[t] : 0;
    s[t] = v;
    __syncthreads();
    for (int off = 1; off < 128; off <<= 1) {
        int x = (t >= off) ? s[t - off] : 0;
        __syncthreads();
        s[t] += x;
        __syncthreads();
    }
    if (t < nb) blksum[t] = s[t] - v;
}

__global__ void scan3(const int* __restrict__ blksum, int n, int e_n, int* __restrict__ row_ptr)
{
    int i = blockIdx.x * 256 + threadIdx.x;
    if (i < n) row_ptr[i] = row_ptr[i] + blksum[i >> 10];
    if (i == n) row_ptr[n] = e_n;
}

// scatter src (pre-gathered) into CSR order
__global__ void scatter_k(const int* __restrict__ src, const int* __restrict__ dst, int e_n,
                          const int* __restrict__ row_ptr, int* __restrict__ cur,
                          int* __restrict__ perm_src)
{
    int e = blockIdx.x * 256 + threadIdx.x;
    if (e < e_n) {
        int d = dst[e];
        int p = atomicAdd(&cur[d], 1);
        perm_src[row_ptr[d] + p] = src[e];
    }
}

// ---------------- K4: fused scores + online softmax + aggregate ----------------
// one 64-lane wave per dst node
__global__ __launch_bounds__(256) void node_fused(
    const float* __restrict__ rec,
    const int* __restrict__ row_ptr, const int* __restrict__ perm_src,
    float* __restrict__ out, int n)
{
    int lane = threadIdx.x & 63;
    int h = lane >> 4, f = lane & 15;
    int v = blockIdx.x * 4 + (threadIdx.x >> 6);
    if (v >= n) return;

    const float* rv = rec + (size_t)v * RECF;
    float zv  = rv[lane];
    float isv = rv[64 + f];
    float erv = rv[84 + h];

    int s0 = row_ptr[v], s1 = row_ptr[v + 1];
    float m = -INFINITY, denom = 0.f, acc = 0.f;

    // software pipeline: preload edge i's record before computing it
    float zu = 0.f, isu = 0.f, elu = 0.f;
    if (s0 < s1) {
        const float* ru = rec + (size_t)perm_src[s0] * RECF;
        zu = ru[lane]; isu = ru[64 + f]; elu = ru[80 + h];
    }
    for (int i = s0; i < s1; i++) {
        // issue next iteration's gathers early
        float zn = zu, in_ = isu, en = elu;
        if (i + 1 < s1) {
            const float* ru = rec + (size_t)perm_src[i + 1] * RECF;
            zn = ru[lane]; in_ = ru[64 + f]; en = ru[80 + h];
        }
        float edp = zu * zv;     // reduce over f -> per-head dot
        float ffp = isu * isv;   // reduce over f -> scalar ff (same in each group)
#pragma unroll
        for (int o = 1; o < 16; o <<= 1) {
            edp += __shfl_xor(edp, o);
            ffp += __shfl_xor(ffp, o);
        }
        float s = fmaxf(edp * ffp, 0.f) * (elu + erv);
        float mn = fmaxf(m, s);
        float c = __expf(m - mn);   // first iter: exp(-inf)=0
        float p = __expf(s - mn);
        denom = denom * c + p;
        acc   = acc * c + p * zu;
        m = mn;
        zu = zn; isu = in_; elu = en;
    }
    out[(size_t)v * 64 + lane] = (s1 > s0) ? (acc / denom) : 0.f;
}

extern "C" void kernel_launch(void* const* d_in, const int* in_sizes, int n_in,
                              void* d_out, int out_size, void* d_ws, size_t ws_size,
                              hipStream_t stream)
{
    const float* feat   = (const float*)d_in[0];
    const int*   src    = (const int*)d_in[1];
    const int*   dst    = (const int*)d_in[2];
    const float* W      = (const float*)d_in[3];
    const float* attn_l = (const float*)d_in[4];
    const float* attn_r = (const float*)d_in[5];
    float* out = (float*)d_out;

    const int n   = in_sizes[0] / DIN;   // 100000
    const int e_n = in_sizes[1];         // 1600000

    // workspace layout
    float* rec     = (float*)d_ws;                       // n*96 floats
    int*   row_ptr = (int*)(rec + (size_t)n * RECF);     // n+1
    int*   cnt     = row_ptr + (n + 1);                  // n
    int*   perm_src= cnt + n;                            // e_n
    int*   blksum  = perm_src + e_n;                     // 128

    int nb = (n + 1023) / 1024;

    hipLaunchKernelGGL(node_transform, dim3((n + 3) / 4), dim3(256), 0, stream,
                       feat, W, attn_l, attn_r, rec, n);

    hipMemsetAsync(cnt, 0, (size_t)n * sizeof(int), stream);
    hipLaunchKernelGGL(count_k, dim3((e_n + 255) / 256), dim3(256), 0, stream, dst, e_n, cnt);
    hipLaunchKernelGGL(scan1, dim3(nb), dim3(256), 0, stream, cnt, n, row_ptr, blksum);
    hipLaunchKernelGGL(scan2, dim3(1), dim3(128), 0, stream, blksum, nb);
    hipLaunchKernelGGL(scan3, dim3((n + 1 + 255) / 256), dim3(256), 0, stream, blksum, n, e_n, row_ptr);
    hipMemsetAsync(cnt, 0, (size_t)n * sizeof(int), stream);
    hipLaunchKernelGGL(scatter_k, dim3((e_n + 255) / 256), dim3(256), 0, stream,
                       src, dst, e_n, row_ptr, cnt, perm_src);

    hipLaunchKernelGGL(node_fused, dim3((n + 3) / 4), dim3(256), 0, stream,
                       rec, row_ptr, perm_src, out, n);
}

// Round 3
// 381.142 us; speedup vs baseline: 2.7430x; 1.3435x over previous
//
#include <hip/hip_runtime.h>
#include <hip/hip_bf16.h>
#include <math.h>

#define DIN 64
#define RECF 96   // floats per packed node record: z[64], inv_s[16], el[4], er[4], pad[8]

// ---- DPP 16-lane row sum (butterfly: xor1, xor2, ror4, ror8) -> sum in all 16 lanes
template<int CTRL>
__device__ __forceinline__ float dppmov(float x) {
    union { float f; int i; } u, r;
    u.f = x;
    r.i = __builtin_amdgcn_update_dpp(0, u.i, CTRL, 0xF, 0xF, true);
    return r.f;
}
__device__ __forceinline__ float rowsum16(float x) {
    x += dppmov<0xB1>(x);    // quad_perm(1,0,3,2) = xor1
    x += dppmov<0x4E>(x);    // quad_perm(2,3,0,1) = xor2
    x += dppmov<0x124>(x);   // row_ror:4
    x += dppmov<0x128>(x);   // row_ror:8
    return x;
}

// ---------------- K1: node transform -> packed record (+ fused edge counting) ----------------
__global__ __launch_bounds__(256) void node_transform(
    const float* __restrict__ feat, const float* __restrict__ W,
    const float* __restrict__ attn_l, const float* __restrict__ attn_r,
    const int* __restrict__ dst, int e_n, int* __restrict__ cnt,
    float* __restrict__ rec, int n)
{
    // fused edge counting (grid-stride over edges)
    for (int e = blockIdx.x * 256 + threadIdx.x; e < e_n; e += gridDim.x * 256)
        atomicAdd(&cnt[dst[e]], 1);

    __shared__ float Wt[64 * 65];   // transposed + padded
    for (int i = threadIdx.x; i < 4096; i += 256)
        Wt[(i & 63) * 65 + (i >> 6)] = W[i];
    __syncthreads();

    int lane = threadIdx.x & 63;
    int h = lane >> 4, f = lane & 15;
    float al = attn_l[lane];
    float ar = attn_r[lane];

    int nidx = blockIdx.x * 4 + (threadIdx.x >> 6);
    if (nidx >= n) return;

    float fv = feat[nidx * 64 + lane];
    float zv = 0.f;
#pragma unroll
    for (int d = 0; d < 64; d++)
        zv += __shfl(fv, d) * Wt[d * 65 + lane];

    float elv = rowsum16(zv * al);
    float erv = rowsum16(zv * ar);

    float sq = zv * zv;
    sq += __shfl_xor(sq, 16);
    sq += __shfl_xor(sq, 32);
    float isv = 1.0f / fmaxf(sq, 1e-3f);

    float* r = rec + (size_t)nidx * RECF;
    r[lane] = zv;
    if (h == 0) r[64 + f] = isv;
    if (f == 0) {
        r[80 + h] = elv;
        r[84 + h] = erv;
    }
}

// ---------------- CSR scan ----------------
__global__ __launch_bounds__(256) void scan1(const int* __restrict__ cnt, int n,
                                             int* __restrict__ excl, int* __restrict__ blksum)
{
    __shared__ int sums[256];
    int t = threadIdx.x;
    int base = blockIdx.x * 1024 + t * 4;
    int v[4];
    int tot = 0;
#pragma unroll
    for (int k = 0; k < 4; k++) {
        int idx = base + k;
        v[k] = (idx < n) ? cnt[idx] : 0;
        tot += v[k];
    }
    sums[t] = tot;
    __syncthreads();
    for (int off = 1; off < 256; off <<= 1) {
        int x = (t >= off) ? sums[t - off] : 0;
        __syncthreads();
        sums[t] += x;
        __syncthreads();
    }
    int run = sums[t] - tot;
#pragma unroll
    for (int k = 0; k < 4; k++) {
        int idx = base + k;
        if (idx < n) excl[idx] = run;
        run += v[k];
    }
    if (t == 255) blksum[blockIdx.x] = sums[255];
}

__global__ __launch_bounds__(128) void scan2(int* __restrict__ blksum, int nb)
{
    __shared__ int s[128];
    int t = threadIdx.x;
    int v = (t < nb) ? blksum[t] : 0;
    s[t] = v;
    __syncthreads();
    for (int off = 1; off < 128; off <<= 1) {
        int x = (t >= off) ? s[t - off] : 0;
        __syncthreads();
        s[t] += x;
        __syncthreads();
    }
    if (t < nb) blksum[t] = s[t] - v;
}

// scatter src into CSR order; row base computed inline (excl + blksum)
__global__ void scatter_k(const int* __restrict__ src, const int* __restrict__ dst, int e_n,
                          const int* __restrict__ excl, const int* __restrict__ blksum,
                          int* __restrict__ cur, int* __restrict__ perm_src)
{
    int e = blockIdx.x * 256 + threadIdx.x;
    if (e < e_n) {
        int d = dst[e];
        int p = atomicAdd(&cur[d], 1);
        perm_src[excl[d] + blksum[d >> 10] + p] = src[e];
    }
}

// ---------------- K4: fused scores + deferred-max online softmax + aggregate ----------------
__global__ __launch_bounds__(256) void node_fused(
    const float* __restrict__ rec,
    const int* __restrict__ excl, const int* __restrict__ blksum,
    const int* __restrict__ perm_src,
    float* __restrict__ out, int n, int e_n)
{
    int lane = threadIdx.x & 63;
    int h = lane >> 4, f = lane & 15;
    int v = blockIdx.x * 4 + (threadIdx.x >> 6);
    if (v >= n) return;

    int s0 = excl[v] + blksum[v >> 10];
    int s1 = (v + 1 < n) ? (excl[v + 1] + blksum[(v + 1) >> 10]) : e_n;

    const float* rv = rec + (size_t)v * RECF;
    float zv  = rv[lane];
    float isv = rv[64 + f];
    float erv = rv[84 + h];

    float m = -INFINITY, denom = 0.f, acc = 0.f;

    // prefetch first pair of src indices
    int pu0 = 0, pu1 = 0;
    if (s0 < s1) {
        pu0 = perm_src[s0];
        pu1 = perm_src[(s0 + 1 < s1) ? s0 + 1 : s1 - 1];
    }

    for (int i = s0; i < s1; i += 2) {
        int u0 = pu0, u1 = pu1;
        bool dup = (i + 1 >= s1);
        // prefetch next pair's indices
        int i2 = i + 2;
        if (i2 < s1) {
            pu0 = perm_src[i2];
            pu1 = perm_src[(i2 + 1 < s1) ? i2 + 1 : s1 - 1];
        }
        const float* r0 = rec + (size_t)u0 * RECF;
        const float* r1 = rec + (size_t)u1 * RECF;
        float zu0 = r0[lane],    zu1 = r1[lane];
        float is0 = r0[64 + f],  is1 = r1[64 + f];
        float el0 = r0[80 + h],  el1 = r1[80 + h];

        float e0 = rowsum16(zu0 * zv);
        float f0 = rowsum16(is0 * isv);
        float e1 = rowsum16(zu1 * zv);
        float f1 = rowsum16(is1 * isv);

        float sA = fmaxf(e0 * f0, 0.f) * (el0 + erv);
        float sB = fmaxf(e1 * f1, 0.f) * (el1 + erv);
        float w1 = dup ? 0.f : 1.f;
        float smax = fmaxf(sA, dup ? sA : sB);

        if (smax > m + 8.f) {      // deferred-max rescale (rare after warmup)
            float c = __expf(m - smax);   // first iter: exp(-inf)=0 zeroes state
            denom *= c;
            acc   *= c;
            m = smax;
        }
        float pA = __expf(sA - m);
        float pB = __expf(sB - m) * w1;
        denom += pA + pB;
        acc   += pA * zu0 + pB * zu1;
    }
    out[(size_t)v * 64 + lane] = (s1 > s0) ? (acc / denom) : 0.f;
}

extern "C" void kernel_launch(void* const* d_in, const int* in_sizes, int n_in,
                              void* d_out, int out_size, void* d_ws, size_t ws_size,
                              hipStream_t stream)
{
    const float* feat   = (const float*)d_in[0];
    const int*   src    = (const int*)d_in[1];
    const int*   dst    = (const int*)d_in[2];
    const float* W      = (const float*)d_in[3];
    const float* attn_l = (const float*)d_in[4];
    const float* attn_r = (const float*)d_in[5];
    float* out = (float*)d_out;

    const int n   = in_sizes[0] / DIN;   // 100000
    const int e_n = in_sizes[1];         // 1600000

    // workspace layout
    float* rec      = (float*)d_ws;                      // n*96 floats
    int*   excl     = (int*)(rec + (size_t)n * RECF);    // n
    int*   cnt      = excl + n;                          // n  } zeroed together
    int*   cur      = cnt + n;                           // n  }
    int*   perm_src = cur + n;                           // e_n
    int*   blksum   = perm_src + e_n;                    // 128

    int nb = (n + 1023) / 1024;
    int nblk = (n + 3) / 4;

    hipMemsetAsync(cnt, 0, (size_t)2 * n * sizeof(int), stream);  // cnt + cur

    hipLaunchKernelGGL(node_transform, dim3(nblk), dim3(256), 0, stream,
                       feat, W, attn_l, attn_r, dst, e_n, cnt, rec, n);

    hipLaunchKernelGGL(scan1, dim3(nb), dim3(256), 0, stream, cnt, n, excl, blksum);
    hipLaunchKernelGGL(scan2, dim3(1), dim3(128), 0, stream, blksum, nb);

    hipLaunchKernelGGL(scatter_k, dim3((e_n + 255) / 256), dim3(256), 0, stream,
                       src, dst, e_n, excl, blksum, cur, perm_src);

    hipLaunchKernelGGL(node_fused, dim3(nblk), dim3(256), 0, stream,
                       rec, excl, blksum, perm_src, out, n, e_n);
}

// Round 4
// 313.786 us; speedup vs baseline: 3.3319x; 1.2147x over previous
//
#include <hip/hip_runtime.h>
#include <hip/hip_bf16.h>
#include <math.h>

#define DIN 64
#define RECF 96   // floats per packed node record: z[64], inv_s[16], el[4], er[4], pad[8]

// ---- DPP 16-lane row sum (butterfly: xor1, xor2, ror4, ror8) -> sum in all 16 lanes
template<int CTRL>
__device__ __forceinline__ float dppmov(float x) {
    union { float f; int i; } u, r;
    u.f = x;
    r.i = __builtin_amdgcn_update_dpp(0, u.i, CTRL, 0xF, 0xF, true);
    return r.f;
}
__device__ __forceinline__ float rowsum16(float x) {
    x += dppmov<0xB1>(x);    // quad_perm(1,0,3,2) = xor1
    x += dppmov<0x4E>(x);    // quad_perm(2,3,0,1) = xor2
    x += dppmov<0x124>(x);   // row_ror:4
    x += dppmov<0x128>(x);   // row_ror:8
    return x;
}

// ---------------- K1: node transform -> packed record (+ fused edge counting) ----------------
// Each lane holds W row `lane` (64 VGPRs). feat row is wave-uniform -> scalar loads.
// Block = 256 threads = 4 waves; each wave does 4 nodes -> 16 nodes/block.
__global__ __launch_bounds__(256) void node_transform(
    const float* __restrict__ feat, const float* __restrict__ W,
    const float* __restrict__ attn_l, const float* __restrict__ attn_r,
    const int* __restrict__ dst, int e_n, int* __restrict__ cnt,
    float* __restrict__ rec, int n)
{
    // fused edge counting (grid is sized so each thread handles exactly ~1 edge)
    for (int e = blockIdx.x * 256 + threadIdx.x; e < e_n; e += gridDim.x * 256)
        atomicAdd(&cnt[dst[e]], 1);

    int lane = threadIdx.x & 63;
    int h = lane >> 4, f = lane & 15;

    // W row `lane` into registers: z[c] = sum_d feat[d] * W[c*64+d]
    float4 wv[16];
    const float4* Wr = (const float4*)(W + (size_t)lane * 64);
#pragma unroll
    for (int i = 0; i < 16; i++) wv[i] = Wr[i];

    float al = attn_l[lane];
    float ar = attn_r[lane];

    int base = blockIdx.x * 16 + (threadIdx.x >> 6) * 4;
#pragma unroll 1
    for (int k = 0; k < 4; k++) {
        int nidx = base + k;
        if (nidx >= n) break;
        // wave-uniform feat row pointer -> scalar loads
        int nu = __builtin_amdgcn_readfirstlane(nidx);
        const float4* frow = (const float4*)(feat + (size_t)nu * 64);

        float zv = 0.f;
#pragma unroll
        for (int i = 0; i < 16; i++) {
            float4 fd = frow[i];
            zv += fd.x * wv[i].x + fd.y * wv[i].y + fd.z * wv[i].z + fd.w * wv[i].w;
        }

        float elv = rowsum16(zv * al);
        float erv = rowsum16(zv * ar);

        float sq = zv * zv;
        sq += __shfl_xor(sq, 16);
        sq += __shfl_xor(sq, 32);
        float isv = 1.0f / fmaxf(sq, 1e-3f);

        float* r = rec + (size_t)nu * RECF;
        r[lane] = zv;
        if (h == 0) r[64 + f] = isv;
        if (f == 0) {
            r[80 + h] = elv;
            r[84 + h] = erv;
        }
    }
}

// ---------------- CSR scan ----------------
__global__ __launch_bounds__(256) void scan1(const int* __restrict__ cnt, int n,
                                             int* __restrict__ excl, int* __restrict__ blksum)
{
    __shared__ int sums[256];
    int t = threadIdx.x;
    int base = blockIdx.x * 1024 + t * 4;
    int v[4];
    int tot = 0;
#pragma unroll
    for (int k = 0; k < 4; k++) {
        int idx = base + k;
        v[k] = (idx < n) ? cnt[idx] : 0;
        tot += v[k];
    }
    sums[t] = tot;
    __syncthreads();
    for (int off = 1; off < 256; off <<= 1) {
        int x = (t >= off) ? sums[t - off] : 0;
        __syncthreads();
        sums[t] += x;
        __syncthreads();
    }
    int run = sums[t] - tot;
#pragma unroll
    for (int k = 0; k < 4; k++) {
        int idx = base + k;
        if (idx < n) excl[idx] = run;
        run += v[k];
    }
    if (t == 255) blksum[blockIdx.x] = sums[255];
}

__global__ __launch_bounds__(128) void scan2(int* __restrict__ blksum, int nb)
{
    __shared__ int s[128];
    int t = threadIdx.x;
    int v = (t < nb) ? blksum[t] : 0;
    s[t] = v;
    __syncthreads();
    for (int off = 1; off < 128; off <<= 1) {
        int x = (t >= off) ? s[t - off] : 0;
        __syncthreads();
        s[t] += x;
        __syncthreads();
    }
    if (t < nb) blksum[t] = s[t] - v;
}

// scatter src into CSR order; row base computed inline (excl + blksum)
__global__ void scatter_k(const int* __restrict__ src, const int* __restrict__ dst, int e_n,
                          const int* __restrict__ excl, const int* __restrict__ blksum,
                          int* __restrict__ cur, int* __restrict__ perm_src)
{
    int e = blockIdx.x * 256 + threadIdx.x;
    if (e < e_n) {
        int d = dst[e];
        int p = atomicAdd(&cur[d], 1);
        perm_src[excl[d] + blksum[d >> 10] + p] = src[e];
    }
}

// ---------------- K4: fused scores + deferred-max online softmax + aggregate ----------------
__global__ __launch_bounds__(256) void node_fused(
    const float* __restrict__ rec,
    const int* __restrict__ excl, const int* __restrict__ blksum,
    const int* __restrict__ perm_src,
    float* __restrict__ out, int n, int e_n)
{
    int lane = threadIdx.x & 63;
    int h = lane >> 4, f = lane & 15;
    int v = blockIdx.x * 4 + (threadIdx.x >> 6);
    if (v >= n) return;

    int s0 = excl[v] + blksum[v >> 10];
    int s1 = (v + 1 < n) ? (excl[v + 1] + blksum[(v + 1) >> 10]) : e_n;

    const float* rv = rec + (size_t)v * RECF;
    float zv  = rv[lane];
    float isv = rv[64 + f];
    float erv = rv[84 + h];

    float m = -INFINITY, denom = 0.f, acc = 0.f;

    // prefetch first pair of src indices
    int pu0 = 0, pu1 = 0;
    if (s0 < s1) {
        pu0 = perm_src[s0];
        pu1 = perm_src[(s0 + 1 < s1) ? s0 + 1 : s1 - 1];
    }

    for (int i = s0; i < s1; i += 2) {
        int u0 = pu0, u1 = pu1;
        bool dup = (i + 1 >= s1);
        // prefetch next pair's indices
        int i2 = i + 2;
        if (i2 < s1) {
            pu0 = perm_src[i2];
            pu1 = perm_src[(i2 + 1 < s1) ? i2 + 1 : s1 - 1];
        }
        const float* r0 = rec + (size_t)u0 * RECF;
        const float* r1 = rec + (size_t)u1 * RECF;
        float zu0 = r0[lane],    zu1 = r1[lane];
        float is0 = r0[64 + f],  is1 = r1[64 + f];
        float el0 = r0[80 + h],  el1 = r1[80 + h];

        float e0 = rowsum16(zu0 * zv);
        float f0 = rowsum16(is0 * isv);
        float e1 = rowsum16(zu1 * zv);
        float f1 = rowsum16(is1 * isv);

        float sA = fmaxf(e0 * f0, 0.f) * (el0 + erv);
        float sB = fmaxf(e1 * f1, 0.f) * (el1 + erv);
        float w1 = dup ? 0.f : 1.f;
        float smax = fmaxf(sA, dup ? sA : sB);

        if (smax > m + 8.f) {      // deferred-max rescale (rare after warmup)
            float c = __expf(m - smax);   // first iter: exp(-inf)=0 zeroes state
            denom *= c;
            acc   *= c;
            m = smax;
        }
        float pA = __expf(sA - m);
        float pB = __expf(sB - m) * w1;
        denom += pA + pB;
        acc   += pA * zu0 + pB * zu1;
    }
    out[(size_t)v * 64 + lane] = (s1 > s0) ? (acc / denom) : 0.f;
}

extern "C" void kernel_launch(void* const* d_in, const int* in_sizes, int n_in,
                              void* d_out, int out_size, void* d_ws, size_t ws_size,
                              hipStream_t stream)
{
    const float* feat   = (const float*)d_in[0];
    const int*   src    = (const int*)d_in[1];
    const int*   dst    = (const int*)d_in[2];
    const float* W      = (const float*)d_in[3];
    const float* attn_l = (const float*)d_in[4];
    const float* attn_r = (const float*)d_in[5];
    float* out = (float*)d_out;

    const int n   = in_sizes[0] / DIN;   // 100000
    const int e_n = in_sizes[1];         // 1600000

    // workspace layout
    float* rec      = (float*)d_ws;                      // n*96 floats
    int*   excl     = (int*)(rec + (size_t)n * RECF);    // n
    int*   cnt      = excl + n;                          // n  } zeroed together
    int*   cur      = cnt + n;                           // n  }
    int*   perm_src = cur + n;                           // e_n
    int*   blksum   = perm_src + e_n;                    // 128

    int nb = (n + 1023) / 1024;
    int nblk = (n + 15) / 16;

    hipMemsetAsync(cnt, 0, (size_t)2 * n * sizeof(int), stream);  // cnt + cur

    hipLaunchKernelGGL(node_transform, dim3(nblk), dim3(256), 0, stream,
                       feat, W, attn_l, attn_r, dst, e_n, cnt, rec, n);

    hipLaunchKernelGGL(scan1, dim3(nb), dim3(256), 0, stream, cnt, n, excl, blksum);
    hipLaunchKernelGGL(scan2, dim3(1), dim3(128), 0, stream, blksum, nb);

    hipLaunchKernelGGL(scatter_k, dim3((e_n + 255) / 256), dim3(256), 0, stream,
                       src, dst, e_n, excl, blksum, cur, perm_src);

    hipLaunchKernelGGL(node_fused, dim3(nblk * 4), dim3(256), 0, stream,
                       rec, excl, blksum, perm_src, out, n, e_n);
}

// Round 5
// 274.270 us; speedup vs baseline: 3.8119x; 1.1441x over previous
//
#include <hip/hip_runtime.h>
#include <hip/hip_fp16.h>
#include <math.h>

#define DIN 64
#define RECF 64   // floats per record (256B): z fp16[64] (128B) | inv_s f32[16] | el f32[4] | er f32[4] (el/er pre-scaled by log2e)
#define LOG2E 1.44269504f
#define DEFER_THR 11.5415603f   // 8 * log2(e)

__device__ __forceinline__ float fast_exp2(float x) {
    float r; asm("v_exp_f32 %0, %1" : "=v"(r) : "v"(x)); return r;
}

// ---- DPP 16-lane row sum (butterfly: xor1, xor2, ror4, ror8) -> sum in all 16 lanes
template<int CTRL>
__device__ __forceinline__ float dppmov(float x) {
    union { float f; int i; } u, r;
    u.f = x;
    r.i = __builtin_amdgcn_update_dpp(0, u.i, CTRL, 0xF, 0xF, true);
    return r.f;
}
__device__ __forceinline__ float rowsum16(float x) {
    x += dppmov<0xB1>(x);    // quad_perm xor1
    x += dppmov<0x4E>(x);    // quad_perm xor2
    x += dppmov<0x124>(x);   // row_ror:4
    x += dppmov<0x128>(x);   // row_ror:8
    return x;
}

// ---------------- K1: node transform -> packed record (+ fused edge counting) ----------------
__global__ __launch_bounds__(256) void node_transform(
    const float* __restrict__ feat, const float* __restrict__ W,
    const float* __restrict__ attn_l, const float* __restrict__ attn_r,
    const int* __restrict__ dst, int e_n, int* __restrict__ cnt,
    float* __restrict__ rec, int n)
{
    for (int e = blockIdx.x * 256 + threadIdx.x; e < e_n; e += gridDim.x * 256)
        atomicAdd(&cnt[dst[e]], 1);

    int lane = threadIdx.x & 63;
    int h = lane >> 4, f = lane & 15;

    float4 wv[16];
    const float4* Wr = (const float4*)(W + (size_t)lane * 64);
#pragma unroll
    for (int i = 0; i < 16; i++) wv[i] = Wr[i];

    float al = attn_l[lane];
    float ar = attn_r[lane];

    int base = blockIdx.x * 16 + (threadIdx.x >> 6) * 4;
#pragma unroll 1
    for (int k = 0; k < 4; k++) {
        int nidx = base + k;
        if (nidx >= n) break;
        int nu = __builtin_amdgcn_readfirstlane(nidx);
        const float4* frow = (const float4*)(feat + (size_t)nu * 64);

        float zv = 0.f;
#pragma unroll
        for (int i = 0; i < 16; i++) {
            float4 fd = frow[i];
            zv += fd.x * wv[i].x + fd.y * wv[i].y + fd.z * wv[i].z + fd.w * wv[i].w;
        }

        float elv = rowsum16(zv * al) * LOG2E;
        float erv = rowsum16(zv * ar) * LOG2E;

        float sq = zv * zv;
        sq += __shfl_xor(sq, 16);
        sq += __shfl_xor(sq, 32);
        float isv = 1.0f / fmaxf(sq, 1e-3f);

        float* r = rec + (size_t)nu * RECF;
        ((__half*)r)[lane] = __float2half_rn(zv);
        if (h == 0) r[32 + f] = isv;
        if (f == 0) {
            r[48 + h] = elv;
            r[52 + h] = erv;
        }
    }
}

// ---------------- CSR scan ----------------
__global__ __launch_bounds__(256) void scan1(const int* __restrict__ cnt, int n,
                                             int* __restrict__ excl, int* __restrict__ blksum)
{
    __shared__ int sums[256];
    int t = threadIdx.x;
    int base = blockIdx.x * 1024 + t * 4;
    int v[4];
    int tot = 0;
#pragma unroll
    for (int k = 0; k < 4; k++) {
        int idx = base + k;
        v[k] = (idx < n) ? cnt[idx] : 0;
        tot += v[k];
    }
    sums[t] = tot;
    __syncthreads();
    for (int off = 1; off < 256; off <<= 1) {
        int x = (t >= off) ? sums[t - off] : 0;
        __syncthreads();
        sums[t] += x;
        __syncthreads();
    }
    int run = sums[t] - tot;
#pragma unroll
    for (int k = 0; k < 4; k++) {
        int idx = base + k;
        if (idx < n) excl[idx] = run;
        run += v[k];
    }
    if (t == 255) blksum[blockIdx.x] = sums[255];
}

__global__ __launch_bounds__(128) void scan2(int* __restrict__ blksum, int nb)
{
    __shared__ int s[128];
    int t = threadIdx.x;
    int v = (t < nb) ? blksum[t] : 0;
    s[t] = v;
    __syncthreads();
    for (int off = 1; off < 128; off <<= 1) {
        int x = (t >= off) ? s[t - off] : 0;
        __syncthreads();
        s[t] += x;
        __syncthreads();
    }
    if (t < nb) blksum[t] = s[t] - v;
}

__global__ void scatter_k(const int* __restrict__ src, const int* __restrict__ dst, int e_n,
                          const int* __restrict__ excl, const int* __restrict__ blksum,
                          int* __restrict__ cur, int* __restrict__ perm_src)
{
    int e = blockIdx.x * 256 + threadIdx.x;
    if (e < e_n) {
        int d = dst[e];
        int p = atomicAdd(&cur[d], 1);
        perm_src[excl[d] + blksum[d >> 10] + p] = src[e];
    }
}

// ---------------- K4: fused scores + deferred-max online softmax + aggregate ----------------
__global__ __launch_bounds__(256) void node_fused(
    const float* __restrict__ rec,
    const int* __restrict__ excl, const int* __restrict__ blksum,
    const int* __restrict__ perm_src,
    float* __restrict__ out, int n, int e_n)
{
    int lane = threadIdx.x & 63;
    int h = lane >> 4, f = lane & 15;
    int v = blockIdx.x * 4 + (threadIdx.x >> 6);
    if (v >= n) return;
    v = __builtin_amdgcn_readfirstlane(v);

    int s0 = __builtin_amdgcn_readfirstlane(excl[v] + blksum[v >> 10]);
    int s1 = (v + 1 < n) ? (excl[v + 1] + blksum[(v + 1) >> 10]) : e_n;
    s1 = __builtin_amdgcn_readfirstlane(s1);

    if (s0 >= s1) { out[(size_t)v * 64 + lane] = 0.f; return; }

    const float* rv = rec + (size_t)v * RECF;
    float zv  = __half2float(((const __half*)rv)[lane]);
    float isv = rv[32 + f];
    float erv = rv[52 + h];

    float m = -INFINITY, denom = 0.f, acc = 0.f;
    int last = s1 - 1;

    // pipeline: records of current pair in regs; indices of next pair in SGPRs
    int u0 = __builtin_amdgcn_readfirstlane(perm_src[s0]);
    int u1 = __builtin_amdgcn_readfirstlane(perm_src[(s0 + 1 <= last) ? s0 + 1 : last]);
    {
        const float* r0 = rec + (size_t)u0 * RECF;
        const float* r1 = rec + (size_t)u1 * RECF;
        // fallthrough into named registers via the loop-carried vars below
        // (loaded here)
        // za..eb declared next
    }
    const float* r0i = rec + (size_t)u0 * RECF;
    const float* r1i = rec + (size_t)u1 * RECF;
    float za = __half2float(((const __half*)r0i)[lane]);
    float ia = r0i[32 + f];
    float ea = r0i[48 + h];
    float zb = __half2float(((const __half*)r1i)[lane]);
    float ib = r1i[32 + f];
    float eb = r1i[48 + h];
    int n0 = __builtin_amdgcn_readfirstlane(perm_src[(s0 + 2 <= last) ? s0 + 2 : last]);
    int n1 = __builtin_amdgcn_readfirstlane(perm_src[(s0 + 3 <= last) ? s0 + 3 : last]);

    int i = s0;
    for (; i + 1 < s1; i += 2) {
        float zu0 = za, is0 = ia, el0 = ea;
        float zu1 = zb, is1 = ib, el1 = eb;
        // issue next pair's record loads
        {
            const float* q0 = rec + (size_t)n0 * RECF;
            const float* q1 = rec + (size_t)n1 * RECF;
            za = __half2float(((const __half*)q0)[lane]);
            ia = q0[32 + f];
            ea = q0[48 + h];
            zb = __half2float(((const __half*)q1)[lane]);
            ib = q1[32 + f];
            eb = q1[48 + h];
        }
        // fetch indices two pairs ahead
        n0 = __builtin_amdgcn_readfirstlane(perm_src[(i + 4 <= last) ? i + 4 : last]);
        n1 = __builtin_amdgcn_readfirstlane(perm_src[(i + 5 <= last) ? i + 5 : last]);

        float e0 = rowsum16(zu0 * zv);
        float f0 = rowsum16(is0 * isv);
        float e1 = rowsum16(zu1 * zv);
        float f1 = rowsum16(is1 * isv);
        float sA = fmaxf(e0 * f0, 0.f) * (el0 + erv);
        float sB = fmaxf(e1 * f1, 0.f) * (el1 + erv);
        float smax = fmaxf(sA, sB);
        if (smax > m + DEFER_THR) {
            float c = fast_exp2(m - smax);
            denom *= c; acc *= c; m = smax;
        }
        float pA = fast_exp2(sA - m);
        float pB = fast_exp2(sB - m);
        denom += pA + pB;
        acc = fmaf(pA, zu0, acc);
        acc = fmaf(pB, zu1, acc);
    }
    if (i < s1) {   // odd tail: za/ia/ea hold edge s1-1
        float e0 = rowsum16(za * zv);
        float f0 = rowsum16(ia * isv);
        float sA = fmaxf(e0 * f0, 0.f) * (ea + erv);
        if (sA > m + DEFER_THR) {
            float c = fast_exp2(m - sA);
            denom *= c; acc *= c; m = sA;
        }
        float pA = fast_exp2(sA - m);
        denom += pA;
        acc = fmaf(pA, za, acc);
    }
    out[(size_t)v * 64 + lane] = acc / denom;
}

extern "C" void kernel_launch(void* const* d_in, const int* in_sizes, int n_in,
                              void* d_out, int out_size, void* d_ws, size_t ws_size,
                              hipStream_t stream)
{
    const float* feat   = (const float*)d_in[0];
    const int*   src    = (const int*)d_in[1];
    const int*   dst    = (const int*)d_in[2];
    const float* W      = (const float*)d_in[3];
    const float* attn_l = (const float*)d_in[4];
    const float* attn_r = (const float*)d_in[5];
    float* out = (float*)d_out;

    const int n   = in_sizes[0] / DIN;   // 100000
    const int e_n = in_sizes[1];         // 1600000

    // workspace layout
    float* rec      = (float*)d_ws;                      // n*64 floats (256B records)
    int*   excl     = (int*)(rec + (size_t)n * RECF);    // n
    int*   cnt      = excl + n;                          // n  } zeroed together
    int*   cur      = cnt + n;                           // n  }
    int*   perm_src = cur + n;                           // e_n
    int*   blksum   = perm_src + e_n;                    // 128

    int nb = (n + 1023) / 1024;
    int nblk = (n + 15) / 16;

    hipMemsetAsync(cnt, 0, (size_t)2 * n * sizeof(int), stream);  // cnt + cur

    hipLaunchKernelGGL(node_transform, dim3(nblk), dim3(256), 0, stream,
                       feat, W, attn_l, attn_r, dst, e_n, cnt, rec, n);

    hipLaunchKernelGGL(scan1, dim3(nb), dim3(256), 0, stream, cnt, n, excl, blksum);
    hipLaunchKernelGGL(scan2, dim3(1), dim3(128), 0, stream, blksum, nb);

    hipLaunchKernelGGL(scatter_k, dim3((e_n + 255) / 256), dim3(256), 0, stream,
                       src, dst, e_n, excl, blksum, cur, perm_src);

    hipLaunchKernelGGL(node_fused, dim3(nblk * 4), dim3(256), 0, stream,
                       rec, excl, blksum, perm_src, out, n, e_n);
}

// Round 6
// 243.060 us; speedup vs baseline: 4.3014x; 1.1284x over previous
//
#include <hip/hip_runtime.h>
#include <hip/hip_fp16.h>
#include <math.h>

#define DIN 64
#define RECF 64   // floats per record (256B): z fp16[64] (128B) | inv_s f32[16] | el f32[4] | er f32[4] (el/er pre-scaled by log2e)
#define LOG2E 1.44269504f
#define DEFER_THR 11.5415603f   // 8 * log2(e)
#define MAXDEG 256              // safety cap (Poisson(16) max ~45; prevents hang on corrupt list)

__device__ __forceinline__ float fast_exp2(float x) {
    float r; asm("v_exp_f32 %0, %1" : "=v"(r) : "v"(x)); return r;
}

// ---- DPP 16-lane row sum (butterfly: xor1, xor2, ror4, ror8) -> sum in all 16 lanes
template<int CTRL>
__device__ __forceinline__ float dppmov(float x) {
    union { float f; int i; } u, r;
    u.f = x;
    r.i = __builtin_amdgcn_update_dpp(0, u.i, CTRL, 0xF, 0xF, true);
    return r.f;
}
__device__ __forceinline__ float rowsum16(float x) {
    x += dppmov<0xB1>(x);    // quad_perm xor1
    x += dppmov<0x4E>(x);    // quad_perm xor2
    x += dppmov<0x124>(x);   // row_ror:4
    x += dppmov<0x128>(x);   // row_ror:8
    return x;
}

// ---------------- K1: node transform -> packed record (+ fused linked-list build) ----------------
__global__ __launch_bounds__(256) void node_transform(
    const float* __restrict__ feat, const float* __restrict__ W,
    const float* __restrict__ attn_l, const float* __restrict__ attn_r,
    const int* __restrict__ dst, int e_n,
    int* __restrict__ head, int* __restrict__ next,
    float* __restrict__ rec, int n)
{
    // build per-dst linked list: 1 atomic per edge, next[] written coalesced
    for (int e = blockIdx.x * 256 + threadIdx.x; e < e_n; e += gridDim.x * 256) {
        int d = dst[e];
        int old = atomicExch(&head[d], e);
        next[e] = old;
    }

    int lane = threadIdx.x & 63;
    int h = lane >> 4, f = lane & 15;

    float4 wv[16];
    const float4* Wr = (const float4*)(W + (size_t)lane * 64);
#pragma unroll
    for (int i = 0; i < 16; i++) wv[i] = Wr[i];

    float al = attn_l[lane];
    float ar = attn_r[lane];

    int base = blockIdx.x * 16 + (threadIdx.x >> 6) * 4;
#pragma unroll 1
    for (int k = 0; k < 4; k++) {
        int nidx = base + k;
        if (nidx >= n) break;
        int nu = __builtin_amdgcn_readfirstlane(nidx);
        const float4* frow = (const float4*)(feat + (size_t)nu * 64);

        float zv = 0.f;
#pragma unroll
        for (int i = 0; i < 16; i++) {
            float4 fd = frow[i];
            zv += fd.x * wv[i].x + fd.y * wv[i].y + fd.z * wv[i].z + fd.w * wv[i].w;
        }

        float elv = rowsum16(zv * al) * LOG2E;
        float erv = rowsum16(zv * ar) * LOG2E;

        float sq = zv * zv;
        sq += __shfl_xor(sq, 16);
        sq += __shfl_xor(sq, 32);
        float isv = 1.0f / fmaxf(sq, 1e-3f);

        float* r = rec + (size_t)nu * RECF;
        ((__half*)r)[lane] = __float2half_rn(zv);
        if (h == 0) r[32 + f] = isv;
        if (f == 0) {
            r[48 + h] = elv;
            r[52 + h] = erv;
        }
    }
}

// ---------------- walk 1: chain length -> cnt (coalesced write) ----------------
__global__ __launch_bounds__(256) void walk_count(
    const int* __restrict__ head, const int* __restrict__ next,
    int* __restrict__ cnt, int n)
{
    int v = blockIdx.x * 256 + threadIdx.x;
    if (v >= n) return;
    int e = head[v], c = 0;
    while (e >= 0 && c < MAXDEG) { c++; e = next[e]; }
    cnt[v] = c;
}

// ---------------- CSR scan ----------------
__global__ __launch_bounds__(256) void scan1(const int* __restrict__ cnt, int n,
                                             int* __restrict__ excl, int* __restrict__ blksum)
{
    __shared__ int sums[256];
    int t = threadIdx.x;
    int base = blockIdx.x * 1024 + t * 4;
    int v[4];
    int tot = 0;
#pragma unroll
    for (int k = 0; k < 4; k++) {
        int idx = base + k;
        v[k] = (idx < n) ? cnt[idx] : 0;
        tot += v[k];
    }
    sums[t] = tot;
    __syncthreads();
    for (int off = 1; off < 256; off <<= 1) {
        int x = (t >= off) ? sums[t - off] : 0;
        __syncthreads();
        sums[t] += x;
        __syncthreads();
    }
    int run = sums[t] - tot;
#pragma unroll
    for (int k = 0; k < 4; k++) {
        int idx = base + k;
        if (idx < n) excl[idx] = run;
        run += v[k];
    }
    if (t == 255) blksum[blockIdx.x] = sums[255];
}

__global__ __launch_bounds__(128) void scan2(int* __restrict__ blksum, int nb)
{
    __shared__ int s[128];
    int t = threadIdx.x;
    int v = (t < nb) ? blksum[t] : 0;
    s[t] = v;
    __syncthreads();
    for (int off = 1; off < 128; off <<= 1) {
        int x = (t >= off) ? s[t - off] : 0;
        __syncthreads();
        s[t] += x;
        __syncthreads();
    }
    if (t < nb) blksum[t] = s[t] - v;
}

// ---------------- walk 2: compact src ids into CSR order (dense line writes) ----------------
__global__ __launch_bounds__(256) void walk_scatter(
    const int* __restrict__ head, const int* __restrict__ next,
    const int* __restrict__ src,
    const int* __restrict__ excl, const int* __restrict__ blksum,
    int* __restrict__ perm_src, int n)
{
    int v = blockIdx.x * 256 + threadIdx.x;
    if (v >= n) return;
    int base = excl[v] + blksum[v >> 10];
    int e = head[v], i = 0;
    while (e >= 0 && i < MAXDEG) {
        perm_src[base + i] = src[e];
        i++;
        e = next[e];
    }
}

// ---------------- K4: fused scores + deferred-max online softmax + aggregate ----------------
__global__ __launch_bounds__(256) void node_fused(
    const float* __restrict__ rec,
    const int* __restrict__ excl, const int* __restrict__ blksum,
    const int* __restrict__ perm_src,
    float* __restrict__ out, int n, int e_n)
{
    int lane = threadIdx.x & 63;
    int h = lane >> 4, f = lane & 15;
    int v = blockIdx.x * 4 + (threadIdx.x >> 6);
    if (v >= n) return;
    v = __builtin_amdgcn_readfirstlane(v);

    int s0 = __builtin_amdgcn_readfirstlane(excl[v] + blksum[v >> 10]);
    int s1 = (v + 1 < n) ? (excl[v + 1] + blksum[(v + 1) >> 10]) : e_n;
    s1 = __builtin_amdgcn_readfirstlane(s1);

    if (s0 >= s1) { out[(size_t)v * 64 + lane] = 0.f; return; }

    const float* rv = rec + (size_t)v * RECF;
    float zv  = __half2float(((const __half*)rv)[lane]);
    float isv = rv[32 + f];
    float erv = rv[52 + h];

    float m = -INFINITY, denom = 0.f, acc = 0.f;
    int last = s1 - 1;

    int u0 = __builtin_amdgcn_readfirstlane(perm_src[s0]);
    int u1 = __builtin_amdgcn_readfirstlane(perm_src[(s0 + 1 <= last) ? s0 + 1 : last]);
    const float* r0i = rec + (size_t)u0 * RECF;
    const float* r1i = rec + (size_t)u1 * RECF;
    float za = __half2float(((const __half*)r0i)[lane]);
    float ia = r0i[32 + f];
    float ea = r0i[48 + h];
    float zb = __half2float(((const __half*)r1i)[lane]);
    float ib = r1i[32 + f];
    float eb = r1i[48 + h];
    int n0 = __builtin_amdgcn_readfirstlane(perm_src[(s0 + 2 <= last) ? s0 + 2 : last]);
    int n1 = __builtin_amdgcn_readfirstlane(perm_src[(s0 + 3 <= last) ? s0 + 3 : last]);

    int i = s0;
    for (; i + 1 < s1; i += 2) {
        float zu0 = za, is0 = ia, el0 = ea;
        float zu1 = zb, is1 = ib, el1 = eb;
        {
            const float* q0 = rec + (size_t)n0 * RECF;
            const float* q1 = rec + (size_t)n1 * RECF;
            za = __half2float(((const __half*)q0)[lane]);
            ia = q0[32 + f];
            ea = q0[48 + h];
            zb = __half2float(((const __half*)q1)[lane]);
            ib = q1[32 + f];
            eb = q1[48 + h];
        }
        n0 = __builtin_amdgcn_readfirstlane(perm_src[(i + 4 <= last) ? i + 4 : last]);
        n1 = __builtin_amdgcn_readfirstlane(perm_src[(i + 5 <= last) ? i + 5 : last]);

        float e0 = rowsum16(zu0 * zv);
        float f0 = rowsum16(is0 * isv);
        float e1 = rowsum16(zu1 * zv);
        float f1 = rowsum16(is1 * isv);
        float sA = fmaxf(e0 * f0, 0.f) * (el0 + erv);
        float sB = fmaxf(e1 * f1, 0.f) * (el1 + erv);
        float smax = fmaxf(sA, sB);
        if (smax > m + DEFER_THR) {
            float c = fast_exp2(m - smax);
            denom *= c; acc *= c; m = smax;
        }
        float pA = fast_exp2(sA - m);
        float pB = fast_exp2(sB - m);
        denom += pA + pB;
        acc = fmaf(pA, zu0, acc);
        acc = fmaf(pB, zu1, acc);
    }
    if (i < s1) {   // odd tail: za/ia/ea hold edge s1-1
        float e0 = rowsum16(za * zv);
        float f0 = rowsum16(ia * isv);
        float sA = fmaxf(e0 * f0, 0.f) * (ea + erv);
        if (sA > m + DEFER_THR) {
            float c = fast_exp2(m - sA);
            denom *= c; acc *= c; m = sA;
        }
        float pA = fast_exp2(sA - m);
        denom += pA;
        acc = fmaf(pA, za, acc);
    }
    out[(size_t)v * 64 + lane] = acc / denom;
}

extern "C" void kernel_launch(void* const* d_in, const int* in_sizes, int n_in,
                              void* d_out, int out_size, void* d_ws, size_t ws_size,
                              hipStream_t stream)
{
    const float* feat   = (const float*)d_in[0];
    const int*   src    = (const int*)d_in[1];
    const int*   dst    = (const int*)d_in[2];
    const float* W      = (const float*)d_in[3];
    const float* attn_l = (const float*)d_in[4];
    const float* attn_r = (const float*)d_in[5];
    float* out = (float*)d_out;

    const int n   = in_sizes[0] / DIN;   // 100000
    const int e_n = in_sizes[1];         // 1600000

    // workspace layout
    float* rec      = (float*)d_ws;                      // n*64 floats (256B records)
    int*   excl     = (int*)(rec + (size_t)n * RECF);    // n
    int*   cnt      = excl + n;                          // n
    int*   head     = cnt + n;                           // n   (memset 0xFF -> -1)
    int*   next     = head + n;                          // e_n
    int*   perm_src = next + e_n;                        // e_n
    int*   blksum   = perm_src + e_n;                    // 128

    int nb = (n + 1023) / 1024;
    int nblk = (n + 15) / 16;
    int nblkN = (n + 255) / 256;

    hipMemsetAsync(head, 0xFF, (size_t)n * sizeof(int), stream);  // head = -1

    hipLaunchKernelGGL(node_transform, dim3(nblk), dim3(256), 0, stream,
                       feat, W, attn_l, attn_r, dst, e_n, head, next, rec, n);

    hipLaunchKernelGGL(walk_count, dim3(nblkN), dim3(256), 0, stream, head, next, cnt, n);

    hipLaunchKernelGGL(scan1, dim3(nb), dim3(256), 0, stream, cnt, n, excl, blksum);
    hipLaunchKernelGGL(scan2, dim3(1), dim3(128), 0, stream, blksum, nb);

    hipLaunchKernelGGL(walk_scatter, dim3(nblkN), dim3(256), 0, stream,
                       head, next, src, excl, blksum, perm_src, n);

    hipLaunchKernelGGL(node_fused, dim3(nblk * 4), dim3(256), 0, stream,
                       rec, excl, blksum, perm_src, out, n, e_n);
}

// Round 7
// 222.085 us; speedup vs baseline: 4.7076x; 1.0944x over previous
//
#include <hip/hip_runtime.h>
#include <hip/hip_fp16.h>
#include <math.h>

#define DIN 64
#define RECF 64   // floats per record (256B): z fp16[64] (128B) | inv_s f32[16] | el f32[4] | er f32[4] (el/er pre-scaled by log2e)
#define LOG2E 1.44269504f
#define DEFER_THR 11.5415603f   // 8 * log2(e)
#define MAXDEG 4096             // safety cap against corrupt chains

__device__ __forceinline__ float fast_exp2(float x) {
    float r; asm("v_exp_f32 %0, %1" : "=v"(r) : "v"(x)); return r;
}

// ---- DPP 16-lane row sum (butterfly: xor1, xor2, ror4, ror8) -> sum in all 16 lanes
template<int CTRL>
__device__ __forceinline__ float dppmov(float x) {
    union { float f; int i; } u, r;
    u.f = x;
    r.i = __builtin_amdgcn_update_dpp(0, u.i, CTRL, 0xF, 0xF, true);
    return r.f;
}
__device__ __forceinline__ float rowsum16(float x) {
    x += dppmov<0xB1>(x);    // quad_perm xor1
    x += dppmov<0x4E>(x);    // quad_perm xor2
    x += dppmov<0x124>(x);   // row_ror:4
    x += dppmov<0x128>(x);   // row_ror:8
    return x;
}

// ---------------- K1: node transform -> packed record (+ fused linked-list build) ----------------
// launch_bounds(256,1): allow high VGPR so the 64-float W row stays register-resident.
__global__ __launch_bounds__(256, 1) void node_transform(
    const float* __restrict__ feat, const float* __restrict__ W,
    const float* __restrict__ attn_l, const float* __restrict__ attn_r,
    const int* __restrict__ src, const int* __restrict__ dst, int e_n,
    int* __restrict__ head, int2* __restrict__ link,
    float* __restrict__ rec, int n)
{
    // build per-dst linked list: 1 atomic per edge; link {next, src} written coalesced
    for (int e = blockIdx.x * 256 + threadIdx.x; e < e_n; e += gridDim.x * 256) {
        int d = dst[e];
        int s = src[e];
        int old = atomicExch(&head[d], e);
        link[e] = make_int2(old, s);
    }

    int lane = threadIdx.x & 63;
    int h = lane >> 4, f = lane & 15;

    // W row `lane` resident in 64 VGPRs
    float4 wv[16];
    const float4* Wr = (const float4*)(W + (size_t)lane * 64);
#pragma unroll
    for (int i = 0; i < 16; i++) wv[i] = Wr[i];

    float al = attn_l[lane];
    float ar = attn_r[lane];

    int base = blockIdx.x * 16 + (threadIdx.x >> 6) * 4;
#pragma unroll 1
    for (int k = 0; k < 4; k++) {
        int nidx = base + k;
        if (nidx >= n) break;
        int nu = __builtin_amdgcn_readfirstlane(nidx);
        const float4* frow = (const float4*)(feat + (size_t)nu * 64);

        // 4 independent accumulators for ILP
        float a0 = 0.f, a1 = 0.f, a2 = 0.f, a3 = 0.f;
#pragma unroll
        for (int i = 0; i < 4; i++) {
            float4 f0 = frow[i * 4 + 0], f1 = frow[i * 4 + 1];
            float4 f2 = frow[i * 4 + 2], f3 = frow[i * 4 + 3];
            a0 += f0.x * wv[i*4+0].x + f0.y * wv[i*4+0].y + f0.z * wv[i*4+0].z + f0.w * wv[i*4+0].w;
            a1 += f1.x * wv[i*4+1].x + f1.y * wv[i*4+1].y + f1.z * wv[i*4+1].z + f1.w * wv[i*4+1].w;
            a2 += f2.x * wv[i*4+2].x + f2.y * wv[i*4+2].y + f2.z * wv[i*4+2].z + f2.w * wv[i*4+2].w;
            a3 += f3.x * wv[i*4+3].x + f3.y * wv[i*4+3].y + f3.z * wv[i*4+3].z + f3.w * wv[i*4+3].w;
        }
        float zv = (a0 + a1) + (a2 + a3);

        float elv = rowsum16(zv * al) * LOG2E;
        float erv = rowsum16(zv * ar) * LOG2E;

        float sq = zv * zv;
        sq += __shfl_xor(sq, 16);
        sq += __shfl_xor(sq, 32);
        float isv = 1.0f / fmaxf(sq, 1e-3f);

        float* r = rec + (size_t)nu * RECF;
        ((__half*)r)[lane] = __float2half_rn(zv);
        if (h == 0) r[32 + f] = isv;
        if (f == 0) {
            r[48 + h] = elv;
            r[52 + h] = erv;
        }
    }
}

// ---------------- K2: fused scores + deferred-max online softmax + aggregate ----------------
// One wave per dst node; walks the per-dst linked list directly (no CSR).
__global__ __launch_bounds__(256) void node_fused(
    const float* __restrict__ rec,
    const int* __restrict__ head, const int2* __restrict__ link,
    float* __restrict__ out, int n)
{
    int lane = threadIdx.x & 63;
    int h = lane >> 4, f = lane & 15;
    int v = blockIdx.x * 4 + (threadIdx.x >> 6);
    if (v >= n) return;
    v = __builtin_amdgcn_readfirstlane(v);

    int e = __builtin_amdgcn_readfirstlane(head[v]);

    const float* rv = rec + (size_t)v * RECF;
    float zv  = __half2float(((const __half*)rv)[lane]);
    float isv = rv[32 + f];
    float erv = rv[52 + h];

    if (e < 0) { out[(size_t)v * 64 + lane] = 0.f; return; }

    float m = -INFINITY, denom = 0.f, acc = 0.f;

    int2 ln;
    ln.x = __builtin_amdgcn_readfirstlane(link[e].x);
    ln.y = __builtin_amdgcn_readfirstlane(link[e].y);

    int guard = 0;
    while (true) {
        int u  = ln.y;             // src node of this edge (uniform)
        int en = ln.x;             // next edge in chain (uniform)
        bool more = (en >= 0) && (++guard < MAXDEG);
        int2 lnn;
        if (more) {                // prefetch next link while we load/compute this record
            lnn.x = __builtin_amdgcn_readfirstlane(link[en].x);
            lnn.y = __builtin_amdgcn_readfirstlane(link[en].y);
        }

        const float* ru = rec + (size_t)u * RECF;
        float zu = __half2float(((const __half*)ru)[lane]);
        float iu = ru[32 + f];
        float eu = ru[48 + h];

        float edp = rowsum16(zu * zv);
        float ffp = rowsum16(iu * isv);
        float s = fmaxf(edp * ffp, 0.f) * (eu + erv);

        if (s > m + DEFER_THR) {   // deferred-max rescale (first iter: exp2(-inf)=0 zeroes state)
            float c = fast_exp2(m - s);
            denom *= c; acc *= c; m = s;
        }
        float p = fast_exp2(s - m);
        denom += p;
        acc = fmaf(p, zu, acc);

        if (!more) break;
        ln = lnn;
    }
    out[(size_t)v * 64 + lane] = acc / denom;
}

extern "C" void kernel_launch(void* const* d_in, const int* in_sizes, int n_in,
                              void* d_out, int out_size, void* d_ws, size_t ws_size,
                              hipStream_t stream)
{
    const float* feat   = (const float*)d_in[0];
    const int*   src    = (const int*)d_in[1];
    const int*   dst    = (const int*)d_in[2];
    const float* W      = (const float*)d_in[3];
    const float* attn_l = (const float*)d_in[4];
    const float* attn_r = (const float*)d_in[5];
    float* out = (float*)d_out;

    const int n   = in_sizes[0] / DIN;   // 100000
    const int e_n = in_sizes[1];         // 1600000

    // workspace layout
    float* rec  = (float*)d_ws;                          // n*64 floats (256B records)  = 25.6 MB
    int*   head = (int*)(rec + (size_t)n * RECF);        // n ints (memset 0xFF -> -1)  = 0.4 MB
    int2*  link = (int2*)(head + n);                     // e_n int2 {next, src}        = 12.8 MB

    int nblk = (n + 15) / 16;   // 6250 blocks * 256 threads = exactly e_n threads

    hipMemsetAsync(head, 0xFF, (size_t)n * sizeof(int), stream);  // head = -1

    hipLaunchKernelGGL(node_transform, dim3(nblk), dim3(256), 0, stream,
                       feat, W, attn_l, attn_r, src, dst, e_n, head, link, rec, n);

    hipLaunchKernelGGL(node_fused, dim3(nblk * 4), dim3(256), 0, stream,
                       rec, head, link, out, n);
}